// Round 1
// baseline (155.589 us; speedup 1.0000x reference)
//
#include <hip/hip_runtime.h>
#include <math.h>

// SoftKConv, round 14.
// r13 post-mortem: coalesced gather + rotated LDS landed 62.8 us, bank
// conflicts exactly 0, but NO pipe >50% (VALU 47%, MFMA 9%, HBM 35%) and
// OccupancyPercent 34% (~11 waves/CU). Diagnosis: latency-bound, starved of
// waves. Single-wave workgroups hit the HW 16-WG/CU cap (50% ceiling) and
// 12500 tiny WGs leave ramp/dispatch tails (avg ~11).
// r14: 3 independent node-pipelines per workgroup (192 threads). Per-wave
// LDS slice 8832 B -> 26496 B/block -> 6 blocks/CU = 18 waves/CU (56%),
// WG count 12500 -> 4167. Waves never sync (no barriers, disjoint LDS), so
// per-node math is bit-identical to r13.

typedef __attribute__((ext_vector_type(2)))  _Float16 half2v;
typedef __attribute__((ext_vector_type(4)))  _Float16 half4v;
typedef __attribute__((ext_vector_type(8)))  _Float16 half8;
typedef __attribute__((ext_vector_type(16))) float    f32x16;

#define NK   32
#define DIM  128
// LDS row stride 272 B (64 dwords used + 4 pad); rotation 16*(k&3) dwords.
#define ROWB 272
// waves (independent node streams) per workgroup
#define WPB  3

// ---------------- Kernel 0: WT[n][k] = (f16) W[k][n] -----------------------
__global__ __launch_bounds__(256) void prep(const float* __restrict__ W,
                                            _Float16* __restrict__ WT) {
    int t  = blockIdx.x * 256 + threadIdx.x;   // 0..16383
    int nn = t >> 7, k = t & 127;
    WT[t] = (_Float16)W[k * 128 + nn];
}

// ---------------- Kernel 1: h = feat @ W -> f16, MFMA ----------------------
__global__ __launch_bounds__(64) void gemm128(
    const float* __restrict__ A, const _Float16* __restrict__ WT,
    _Float16* __restrict__ Hq, int n)
{
    const int lane = threadIdx.x;
    const int l31  = lane & 31;
    const int hf   = lane >> 5;

    const int row  = blockIdx.x * 32 + l31;
    const int rowc = row < n ? row : n - 1;

    f32x16 acc[4];
#pragma unroll
    for (int t = 0; t < 4; ++t)
#pragma unroll
        for (int i = 0; i < 16; ++i) acc[t][i] = 0.0f;

    const float* ap = A + (size_t)rowc * 128 + 8 * hf;
#pragma unroll
    for (int s = 0; s < 8; ++s) {
        float4 b0 = *reinterpret_cast<const float4*>(ap + 16 * s);
        float4 b1 = *reinterpret_cast<const float4*>(ap + 16 * s + 4);
        half8 bf;
        bf[0] = (_Float16)b0.x; bf[1] = (_Float16)b0.y;
        bf[2] = (_Float16)b0.z; bf[3] = (_Float16)b0.w;
        bf[4] = (_Float16)b1.x; bf[5] = (_Float16)b1.y;
        bf[6] = (_Float16)b1.z; bf[7] = (_Float16)b1.w;
#pragma unroll
        for (int t = 0; t < 4; ++t) {
            half8 af = *reinterpret_cast<const half8*>(
                WT + (size_t)(l31 + 32 * t) * 128 + 16 * s + 8 * hf);
            acc[t] = __builtin_amdgcn_mfma_f32_32x32x16_f16(af, bf, acc[t], 0, 0, 0);
        }
    }

    if (row < n) {
        _Float16* hp = Hq + (size_t)row * 128;
#pragma unroll
        for (int t = 0; t < 4; ++t)
#pragma unroll
            for (int g = 0; g < 4; ++g) {
                half4v hv;
#pragma unroll
                for (int q = 0; q < 4; ++q) hv[q] = (_Float16)acc[t][4 * g + q];
                *reinterpret_cast<half4v*>(hp + 32 * t + 8 * g + 4 * hf) = hv;
            }
    }
}

// ---------------- Kernel 2: per-node soft medoid, pipelined ----------------
// 192 threads = 3 independent waves/block, each wave = its own node stream
// with next-node prefetch. No barriers; per-wave LDS slices are disjoint.
__global__ __launch_bounds__(192, 4) void softk(
    const _Float16* __restrict__ hq, const float* __restrict__ bias,
    const float* __restrict__ tkw, const int* __restrict__ idx,
    float* __restrict__ out, int n)
{
    __shared__ __align__(16) char  fkT[WPB][NK * ROWB];   // 3 x 8704 B
    __shared__ __align__(16) float rbuf[WPB][NK];         // 3 x  128 B

    const int w    = threadIdx.x >> 6;   // wave id in block, 0..2
    const int lane = threadIdx.x & 63;
    const int l31  = lane & 31;
    const int hf   = lane >> 5;
    const int g    = lane >> 4;        // gather row group 0..3
    const int m    = lane & 15;        // gather 16B chunk 0..15
    const int pbase = (lane & 32) + ((lane & 32) >> 3);

    char* fkw = &fkT[w][0];

    // loop-invariant addresses
    const int d0 = 2 * lane;
    const float2 bv = *reinterpret_cast<const float2*>(bias + d0);
    const float4* rb = reinterpret_cast<const float4*>(&rbuf[w][0]);
    // coalesced-write vaddr: row k=4i+g, cols 4m..4m+3 -> 272k + 16*((m+4g)&15)
    const int wbase = ROWB * g + 16 * ((m + 4 * g) & 15);
    // frag-read base (row l31) and rolling rotated column
    const int fbase = ROWB * l31;
    const int uc0   = 4 * hf + 16 * (l31 & 3);       // dword col bias
    // epilogue vaddrs: col lane of row k stored at ((lane + 16*(k&3))&63)
    int eaddr[4];
#pragma unroll
    for (int p = 0; p < 4; ++p) eaddr[p] = 4 * ((lane + 16 * p) & 63);

    const int stride = gridDim.x * WPB;
    int nd = blockIdx.x * WPB + w;
    if (nd >= n) return;

    // ---- prologue: first node's idx/tkw + coalesced gather ----
    int   vid = idx[(size_t)nd * NK + l31];
    float tw  = tkw[(size_t)nd * NK + l31];
    int   mkc = (vid < 0) ? 1 : 0;
    float wc  = mkc ? 0.0f : tw;
    half8 gb[8];
    {
        int idr = mkc ? 0 : vid;                     // per-lane (k=l31) id
#pragma unroll
        for (int i = 0; i < 8; ++i) {
            int idg = __shfl(idr, 4 * i + g, 64);    // row 4i+g's id
            gb[i] = *reinterpret_cast<const half8*>(
                hq + (size_t)idg * DIM + 8 * m);     // lane's 16B of that row
        }
    }

    while (true) {
        const int  ndn = nd + stride;
        const bool hn  = ndn < n;

        // pipeline stage 1: next node's idx/tkw
        int vid_n = 0; float tw_n = 0.0f;
        if (hn) {
            vid_n = idx[(size_t)ndn * NK + l31];
            tw_n  = tkw[(size_t)ndn * NK + l31];
        }

        // ---- coalesced write of gathered rows into rotated LDS ----
#pragma unroll
        for (int i = 0; i < 8; ++i)
            *reinterpret_cast<half8*>(&fkw[1088 * i + wbase]) = gb[i];

        // ---- frag reads (row l31, rotated) + gram MFMA + fdot2 sq ----
        f32x16 acc;
#pragma unroll
        for (int i = 0; i < 16; ++i) acc[i] = 0.0f;
        float sqp = 0.0f;
        int u = uc0;
#pragma unroll
        for (int s = 0; s < 8; ++s) {
            half8 fr = *reinterpret_cast<const half8*>(&fkw[fbase + 4 * (u & 63)]);
            u += 8;
            acc = __builtin_amdgcn_mfma_f32_32x32x16_f16(fr, fr, acc, 0, 0, 0);
            const half2v* p2 = reinterpret_cast<const half2v*>(&fr);
#pragma unroll
            for (int q = 0; q < 4; ++q)
                sqp = __builtin_amdgcn_fdot2(p2[q], p2[q], sqp, false);
        }
        float sq = sqp + __shfl_xor(sqp, 32, 64);

        // pipeline stage 2: next node's coalesced gather (in flight across
        // the dagg/softmax/epilogue tail)
        const int mk_n = (vid_n < 0) ? 1 : 0;
        half8 gb_n[8];
        if (hn) {
            int idr_n = mk_n ? 0 : vid_n;
#pragma unroll
            for (int i = 0; i < 8; ++i) {
                int idg = __shfl(idr_n, 4 * i + g, 64);
                gb_n[i] = *reinterpret_cast<const half8*>(
                    hq + (size_t)idg * DIM + 8 * m);
            }
        }

        // 9th MFMA: acc += -(sq_m + sq_c)/2 -> acc = -d2/2 (hi/lo f16 split)
        {
            _Float16 shi = (_Float16)sq;
            _Float16 slo = (_Float16)(sq - (float)shi);
            _Float16 nh  = (_Float16)(-0.5f * (float)shi);
            _Float16 nl  = (_Float16)(-0.5f * (float)slo);
            _Float16 z   = (_Float16)0.0f, one = (_Float16)1.0f;
            half8 aext = {z, z, z, z, z, z, z, z};
            half8 bext = {z, z, z, z, z, z, z, z};
            if (hf == 0) {
                aext[0] = nh;  aext[1] = nl;  aext[2] = one; aext[3] = one;
                bext[0] = one; bext[1] = one; bext[2] = nh;  bext[3] = nl;
            }
            acc = __builtin_amdgcn_mfma_f32_32x32x16_f16(aext, bext, acc, 0, 0, 0);
        }

        // dagg[c=l31] = sum_m w[m]*dist[m][c]; w[rD] via bpermute; 4-way tree
        float pt[4] = {0.0f, 0.0f, 0.0f, 0.0f};
#pragma unroll
        for (int reg = 0; reg < 16; ++reg) {
            const int c = (reg & 3) + 8 * (reg >> 2);
            float wr = __shfl(wc, pbase + c, 64);        // w[c + 4hf]
            float d2 = fmaxf(-(acc[reg] + acc[reg]), 0.0f);
            float ds = (d2 > 1e-4f) ? __builtin_amdgcn_sqrtf(d2) : 0.0f;
            pt[reg & 3] = fmaf(wr, ds, pt[reg & 3]);
        }
        float part = (pt[0] + pt[1]) + (pt[2] + pt[3]);
        float sA = part + __shfl_xor(part, 32, 64);
        if (mkc || !(sA < 3.4028235e38f)) sA = 3.4028235e38f;

        // fused softmax + weight correction: r = e*w / sum(e*w)
        float x  = -sA;
        float mx = x;
#pragma unroll
        for (int o = 16; o > 0; o >>= 1) mx = fmaxf(mx, __shfl_xor(mx, o, 32));
        float t  = __expf(x - mx) * wc;      // masked lanes: w=0 -> t=0
        float st = t;
#pragma unroll
        for (int o = 16; o > 0; o >>= 1) st += __shfl_xor(st, o, 32);
        float r = t * __builtin_amdgcn_rcpf(st);

        // broadcast r via LDS (dup-write from both halves; benign)
        rbuf[w][l31] = r;

        // ---- epilogue: out[d] = sum_k r_k * fk[k][d]; 2 dims/lane ----
        // lane's dword (cols d0,d0+1) of row k at eaddr[k&3] + 272k (imm).
        float o0 = 0.0f, o1 = 0.0f;
#pragma unroll
        for (int q = 0; q < 8; ++q) {
            float4 rv = rb[q];
            half2v h0 = *reinterpret_cast<const half2v*>(&fkw[ROWB * (4 * q + 0) + eaddr[0]]);
            half2v h1 = *reinterpret_cast<const half2v*>(&fkw[ROWB * (4 * q + 1) + eaddr[1]]);
            half2v h2 = *reinterpret_cast<const half2v*>(&fkw[ROWB * (4 * q + 2) + eaddr[2]]);
            half2v h3 = *reinterpret_cast<const half2v*>(&fkw[ROWB * (4 * q + 3) + eaddr[3]]);
            o0 = fmaf(rv.x, (float)h0[0], o0); o1 = fmaf(rv.x, (float)h0[1], o1);
            o0 = fmaf(rv.y, (float)h1[0], o0); o1 = fmaf(rv.y, (float)h1[1], o1);
            o0 = fmaf(rv.z, (float)h2[0], o0); o1 = fmaf(rv.z, (float)h2[1], o1);
            o0 = fmaf(rv.w, (float)h3[0], o0); o1 = fmaf(rv.w, (float)h3[1], o1);
        }
        float2 ov = { o0 + bv.x, o1 + bv.y };
        *reinterpret_cast<float2*>(out + (size_t)nd * DIM + d0) = ov;

        if (!hn) break;
        // rotate pipeline registers
        nd  = ndn;
        mkc = mk_n;
        wc  = mk_n ? 0.0f : tw_n;
#pragma unroll
        for (int i = 0; i < 8; ++i) gb[i] = gb_n[i];
    }
}

extern "C" void kernel_launch(void* const* d_in, const int* in_sizes, int n_in,
                              void* d_out, int out_size, void* d_ws, size_t ws_size,
                              hipStream_t stream) {
    const float* feat = (const float*)d_in[0];
    const float* W    = (const float*)d_in[1];
    const float* bias = (const float*)d_in[2];
    const float* tkw  = (const float*)d_in[3];
    const int*   idx  = (const int*)d_in[4];
    float* out = (float*)d_out;

    const int n = in_sizes[0] / DIM;                       // 50000
    _Float16* hq = (_Float16*)d_ws;                        // n*128*2 = 12.8 MB
    _Float16* wt = hq + (size_t)n * DIM;                   // 32 KB

    const int gblocks = (n + 31) / 32;                     // 1563 (gemm)
    const int sblocks = (n + 4 * WPB - 1) / (4 * WPB);     // 4167 (softk, 3 waves x ~4 nodes)

    prep<<<64, 256, 0, stream>>>(W, wt);
    gemm128<<<gblocks, 64, 0, stream>>>(feat, wt, hq, n);
    softk<<<sblocks, 192, 0, stream>>>(hq, bias, tkw, idx, out, n);
}